// Round 1
// baseline (679.188 us; speedup 1.0000x reference)
//
#include <hip/hip_runtime.h>
#include <math.h>

#define N_NODES 50000
#define N_EDGES 800000
#define N_GRAPHS 16
#define NODE_F 128
#define HID 64
#define OUT_F 128
#define HEADS 3
#define NEG 0.2f
#define FEAT (HEADS*HID)  // 192

// ---------------- K0: feat = h @ fc_w.T ; el/er attention dots ----------------
#define K0_NB 16
__global__ __launch_bounds__(192) void k0_gemm(
    const float* __restrict__ h, const float* __restrict__ fc_w,
    const float* __restrict__ attn_l, const float* __restrict__ attn_r,
    float* __restrict__ feat, float* __restrict__ el, float* __restrict__ er)
{
  __shared__ float hs[K0_NB][NODE_F];
  const int tid = threadIdx.x;
  const int n0 = blockIdx.x * K0_NB;
  for (int i = tid; i < K0_NB * NODE_F; i += 192) {
    hs[i >> 7][i & 127] = h[(size_t)n0 * NODE_F + i];
  }
  __syncthreads();

  float acc[K0_NB];
#pragma unroll
  for (int m = 0; m < K0_NB; m++) acc[m] = 0.f;
  const float* wrow = fc_w + (size_t)tid * NODE_F;
  for (int k = 0; k < NODE_F; k += 4) {
    float4 w4 = *(const float4*)(wrow + k);
#pragma unroll
    for (int m = 0; m < K0_NB; m++) {
      float4 h4 = *(const float4*)(&hs[m][k]);
      acc[m] = fmaf(w4.x, h4.x, fmaf(w4.y, h4.y, fmaf(w4.z, h4.z, fmaf(w4.w, h4.w, acc[m]))));
    }
  }
#pragma unroll
  for (int m = 0; m < K0_NB; m++) feat[(size_t)(n0 + m) * FEAT + tid] = acc[m];

  // el/er: wave w (tid 0..63 etc) == head w; reduce over d within the wave.
  const int head = tid >> 6, d = tid & 63;
  const float al = attn_l[head * HID + d];
  const float ar = attn_r[head * HID + d];
#pragma unroll
  for (int m = 0; m < K0_NB; m++) {
    float vl = acc[m] * al;
    float vr = acc[m] * ar;
#pragma unroll
    for (int off = 32; off; off >>= 1) {
      vl += __shfl_xor(vl, off, 64);
      vr += __shfl_xor(vr, off, 64);
    }
    if (d == 0) {
      el[(size_t)(n0 + m) * 4 + head] = vl;   // stride-4 pad so K4 can float4-load
      er[(size_t)(n0 + m) * 4 + head] = vr;
    }
  }
}

// ---------------- K1: in-degree histogram ----------------
__global__ void k1_hist(const int* __restrict__ dst, int* __restrict__ deg) {
  int e = blockIdx.x * blockDim.x + threadIdx.x;
  if (e < N_EDGES) atomicAdd(&deg[dst[e]], 1);
}

// ---------------- K2: exclusive scan (single block) ----------------
__global__ __launch_bounds__(1024) void k2_scan(
    const int* __restrict__ deg, int* __restrict__ offs, int* __restrict__ cursor)
{
  const int T = 1024, ITEMS = 49;  // 1024*49 = 50176 >= 50000
  __shared__ int lds[T];
  const int tid = threadIdx.x;
  const int base = tid * ITEMS;
  int s = 0;
  for (int i = 0; i < ITEMS; i++) {
    int idx = base + i;
    if (idx < N_NODES) s += deg[idx];
  }
  lds[tid] = s;
  __syncthreads();
  for (int off = 1; off < T; off <<= 1) {
    int t = (tid >= off) ? lds[tid - off] : 0;
    __syncthreads();
    lds[tid] += t;
    __syncthreads();
  }
  int run = lds[tid] - s;  // exclusive prefix of this chunk
  for (int i = 0; i < ITEMS; i++) {
    int idx = base + i;
    if (idx < N_NODES) {
      offs[idx] = run;
      cursor[idx] = run;
      run += deg[idx];
    }
  }
  if (tid == T - 1) offs[N_NODES] = run;  // == N_EDGES
}

// ---------------- K3: scatter edges into CSR-by-dst ----------------
__global__ void k3_scatter(const int* __restrict__ src, const int* __restrict__ dst,
                           int* __restrict__ cursor, int* __restrict__ csr_src) {
  int e = blockIdx.x * blockDim.x + threadIdx.x;
  if (e < N_EDGES) {
    int d = dst[e];
    int pos = atomicAdd(&cursor[d], 1);
    csr_src[pos] = src[e];
  }
}

// ---------------- K4: per-dst softmax + weighted aggregation + head-mean ----------------
__global__ __launch_bounds__(256) void k4_agg(
    const int* __restrict__ offs, const int* __restrict__ csr_src,
    const float* __restrict__ el4, const float* __restrict__ er4,
    const float* __restrict__ feat, const float* __restrict__ bias,
    float* __restrict__ h_d)
{
  const int n = (blockIdx.x * blockDim.x + threadIdx.x) >> 6;  // wave per node
  const int lane = threadIdx.x & 63;
  if (n >= N_NODES) return;
  const int lo = offs[n], hi = offs[n + 1];
  const float4 erv = ((const float4*)er4)[n];

  // pass 1: per-head max
  float m0 = -INFINITY, m1 = -INFINITY, m2 = -INFINITY;
  for (int pos = lo + lane; pos < hi; pos += 64) {
    int s = csr_src[pos];
    float4 ev = ((const float4*)el4)[s];
    float e0 = ev.x + erv.x; e0 = e0 > 0.f ? e0 : NEG * e0;
    float e1 = ev.y + erv.y; e1 = e1 > 0.f ? e1 : NEG * e1;
    float e2 = ev.z + erv.z; e2 = e2 > 0.f ? e2 : NEG * e2;
    m0 = fmaxf(m0, e0); m1 = fmaxf(m1, e1); m2 = fmaxf(m2, e2);
  }
#pragma unroll
  for (int off = 32; off; off >>= 1) {
    m0 = fmaxf(m0, __shfl_xor(m0, off, 64));
    m1 = fmaxf(m1, __shfl_xor(m1, off, 64));
    m2 = fmaxf(m2, __shfl_xor(m2, off, 64));
  }

  // pass 2: per-head sum of exp
  float s0 = 0.f, s1 = 0.f, s2 = 0.f;
  for (int pos = lo + lane; pos < hi; pos += 64) {
    int s = csr_src[pos];
    float4 ev = ((const float4*)el4)[s];
    float e0 = ev.x + erv.x; e0 = e0 > 0.f ? e0 : NEG * e0;
    float e1 = ev.y + erv.y; e1 = e1 > 0.f ? e1 : NEG * e1;
    float e2 = ev.z + erv.z; e2 = e2 > 0.f ? e2 : NEG * e2;
    s0 += __expf(e0 - m0); s1 += __expf(e1 - m1); s2 += __expf(e2 - m2);
  }
#pragma unroll
  for (int off = 32; off; off >>= 1) {
    s0 += __shfl_xor(s0, off, 64);
    s1 += __shfl_xor(s1, off, 64);
    s2 += __shfl_xor(s2, off, 64);
  }
  const float i0 = s0 > 0.f ? 1.f / s0 : 0.f;
  const float i1 = s1 > 0.f ? 1.f / s1 : 0.f;
  const float i2 = s2 > 0.f ? 1.f / s2 : 0.f;

  // pass 3: aggregate alpha * feat[src]; lane owns dim `lane` for each head
  float a0 = 0.f, a1 = 0.f, a2 = 0.f;
  for (int base = lo; base < hi; base += 64) {
    const int cnt = min(64, hi - base);
    float w0 = 0.f, w1 = 0.f, w2 = 0.f;
    int sj = 0;
    if (lane < cnt) {
      sj = csr_src[base + lane];
      float4 ev = ((const float4*)el4)[sj];
      float e0 = ev.x + erv.x; e0 = e0 > 0.f ? e0 : NEG * e0;
      float e1 = ev.y + erv.y; e1 = e1 > 0.f ? e1 : NEG * e1;
      float e2 = ev.z + erv.z; e2 = e2 > 0.f ? e2 : NEG * e2;
      w0 = __expf(e0 - m0) * i0;
      w1 = __expf(e1 - m1) * i1;
      w2 = __expf(e2 - m2) * i2;
    }
    for (int j = 0; j < cnt; j++) {
      float b0 = __shfl(w0, j, 64);
      float b1 = __shfl(w1, j, 64);
      float b2 = __shfl(w2, j, 64);
      int ss = __shfl(sj, j, 64);
      const float* fr = feat + (size_t)ss * FEAT;
      a0 = fmaf(b0, fr[lane], a0);
      a1 = fmaf(b1, fr[64 + lane], a1);
      a2 = fmaf(b2, fr[128 + lane], a2);
    }
  }
  float o = (a0 + bias[lane] + a1 + bias[64 + lane] + a2 + bias[128 + lane]) * (1.f / 3.f);
  h_d[(size_t)n * HID + lane] = o;
}

// ---------------- K5: per-graph mean pooling (graph_id is sorted) ----------------
__global__ __launch_bounds__(256) void k5_pool(
    const int* __restrict__ graph_id, const float* __restrict__ h_d,
    float* __restrict__ pooled)
{
  const int g = blockIdx.x;
  int lo, hi;
  { int l = 0, h = N_NODES; while (l < h) { int m = (l + h) >> 1; if (graph_id[m] < g) l = m + 1; else h = m; } lo = l; }
  { int l = 0, h = N_NODES; while (l < h) { int m = (l + h) >> 1; if (graph_id[m] < g + 1) l = m + 1; else h = m; } hi = l; }
  const int tid = threadIdx.x;
  const int d = tid & 63, grp = tid >> 6;
  float s = 0.f;
  for (int i = lo + grp; i < hi; i += 4) s += h_d[(size_t)i * HID + d];
  __shared__ float red[256];
  red[tid] = s;
  __syncthreads();
  if (tid < 64) {
    float t = red[tid] + red[64 + tid] + red[128 + tid] + red[192 + tid];
    int cnt = hi - lo;
    pooled[g * HID + d] = t / (float)(cnt > 0 ? cnt : 1);
  }
}

// ---------------- K6: z @ lin1.T, concat, lin2, sigmoid ----------------
__global__ __launch_bounds__(256) void k6_final(
    const float* __restrict__ pooled, const float* __restrict__ z,
    const float* __restrict__ lin1_w, const float* __restrict__ lin1_b,
    const float* __restrict__ lin2_w, const float* __restrict__ lin2_b,
    float* __restrict__ out)
{
  __shared__ float cat[N_GRAPHS][2 * HID];
  const int tid = threadIdx.x;
  for (int i = tid; i < N_GRAPHS * HID; i += 256) {
    cat[i >> 6][i & 63] = pooled[i];
  }
  for (int i = tid; i < N_GRAPHS * HID; i += 256) {
    int g = i >> 6, j = i & 63;
    float s = lin1_b[j];
    const float* zr = z + g * OUT_F;
    const float* wr = lin1_w + j * OUT_F;
    for (int k = 0; k < OUT_F; k += 4) {
      float4 zv = *(const float4*)(zr + k);
      float4 wv = *(const float4*)(wr + k);
      s = fmaf(zv.x, wv.x, fmaf(zv.y, wv.y, fmaf(zv.z, wv.z, fmaf(zv.w, wv.w, s))));
    }
    cat[g][HID + j] = s;
  }
  __syncthreads();
  if (tid < N_GRAPHS) {
    float s = lin2_b[0];
    for (int i = 0; i < 2 * HID; i++) s += cat[tid][i] * lin2_w[i];
    out[tid] = 1.f / (1.f + __expf(-s));
  }
}

extern "C" void kernel_launch(void* const* d_in, const int* in_sizes, int n_in,
                              void* d_out, int out_size, void* d_ws, size_t ws_size,
                              hipStream_t stream) {
  (void)in_sizes; (void)n_in; (void)out_size; (void)ws_size;
  const float* h      = (const float*)d_in[0];
  const float* z      = (const float*)d_in[1];
  const int*   src    = (const int*)d_in[2];
  const int*   dst    = (const int*)d_in[3];
  const int*   gid    = (const int*)d_in[4];
  const float* fc_w   = (const float*)d_in[5];
  const float* attn_l = (const float*)d_in[6];
  const float* attn_r = (const float*)d_in[7];
  const float* bias   = (const float*)d_in[8];
  const float* lin1_w = (const float*)d_in[9];
  const float* lin1_b = (const float*)d_in[10];
  const float* lin2_w = (const float*)d_in[11];
  const float* lin2_b = (const float*)d_in[12];
  float* out = (float*)d_out;

  // workspace layout (~57 MB)
  float* feat   = (float*)d_ws;                          // N*192
  float* el     = feat + (size_t)N_NODES * FEAT;         // N*4 (pad-4)
  float* er     = el + (size_t)N_NODES * 4;              // N*4
  float* h_d    = er + (size_t)N_NODES * 4;              // N*64
  float* pooled = h_d + (size_t)N_NODES * HID;           // 16*64
  int* deg      = (int*)(pooled + N_GRAPHS * HID);       // N+1
  int* offs     = deg + (N_NODES + 1);                   // N+1
  int* cursor   = offs + (N_NODES + 1);                  // N
  int* csr_src  = cursor + N_NODES;                      // E

  hipMemsetAsync(deg, 0, (N_NODES + 1) * sizeof(int), stream);
  k0_gemm<<<N_NODES / K0_NB, 192, 0, stream>>>(h, fc_w, attn_l, attn_r, feat, el, er);
  k1_hist<<<N_EDGES / 256, 256, 0, stream>>>(dst, deg);
  k2_scan<<<1, 1024, 0, stream>>>(deg, offs, cursor);
  k3_scatter<<<N_EDGES / 256, 256, 0, stream>>>(src, dst, cursor, csr_src);
  k4_agg<<<N_NODES / 4, 256, 0, stream>>>(offs, csr_src, el, er, feat, bias, h_d);
  k5_pool<<<N_GRAPHS, 256, 0, stream>>>(gid, h_d, pooled);
  k6_final<<<1, 256, 0, stream>>>(pooled, z, lin1_w, lin1_b, lin2_w, lin2_b, out);
}

// Round 2
// 384.583 us; speedup vs baseline: 1.7660x; 1.7660x over previous
//
#include <hip/hip_runtime.h>
#include <math.h>

#define N_NODES 50000
#define N_EDGES 800000
#define N_GRAPHS 16
#define NODE_F 128
#define HID 64
#define OUT_F 128
#define HEADS 3
#define NEG 0.2f
#define FEAT (HEADS*HID)  // 192

// ---------------- K0: feat = h @ fc_w.T ; el/er attention dots ----------------
#define K0_NB 16
__global__ __launch_bounds__(192) void k0_gemm(
    const float* __restrict__ h, const float* __restrict__ fc_w,
    const float* __restrict__ attn_l, const float* __restrict__ attn_r,
    float* __restrict__ feat, float* __restrict__ el, float* __restrict__ er)
{
  __shared__ float hs[K0_NB][NODE_F];
  const int tid = threadIdx.x;
  const int n0 = blockIdx.x * K0_NB;
  for (int i = tid; i < K0_NB * NODE_F; i += 192) {
    hs[i >> 7][i & 127] = h[(size_t)n0 * NODE_F + i];
  }
  __syncthreads();

  float acc[K0_NB];
#pragma unroll
  for (int m = 0; m < K0_NB; m++) acc[m] = 0.f;
  const float* wrow = fc_w + (size_t)tid * NODE_F;
  for (int k = 0; k < NODE_F; k += 4) {
    float4 w4 = *(const float4*)(wrow + k);
#pragma unroll
    for (int m = 0; m < K0_NB; m++) {
      float4 h4 = *(const float4*)(&hs[m][k]);
      acc[m] = fmaf(w4.x, h4.x, fmaf(w4.y, h4.y, fmaf(w4.z, h4.z, fmaf(w4.w, h4.w, acc[m]))));
    }
  }
#pragma unroll
  for (int m = 0; m < K0_NB; m++) feat[(size_t)(n0 + m) * FEAT + tid] = acc[m];

  // el/er: wave w == head w; reduce over d within the wave.
  const int head = tid >> 6, d = tid & 63;
  const float al = attn_l[head * HID + d];
  const float ar = attn_r[head * HID + d];
#pragma unroll
  for (int m = 0; m < K0_NB; m++) {
    float vl = acc[m] * al;
    float vr = acc[m] * ar;
#pragma unroll
    for (int off = 32; off; off >>= 1) {
      vl += __shfl_xor(vl, off, 64);
      vr += __shfl_xor(vr, off, 64);
    }
    if (d == 0) {
      el[(size_t)(n0 + m) * 4 + head] = vl;   // stride-4 pad so K4 can float4-load
      er[(size_t)(n0 + m) * 4 + head] = vr;
    }
  }
}

// ---------------- K1: in-degree histogram ----------------
__global__ void k1_hist(const int* __restrict__ dst, int* __restrict__ deg) {
  int e = blockIdx.x * blockDim.x + threadIdx.x;
  if (e < N_EDGES) atomicAdd(&deg[dst[e]], 1);
}

// ---------------- K2: coalesced 3-stage exclusive scan ----------------
#define SCAN_T 1024
#define SCAN_NB 49  // ceil(50000/1024)

__global__ __launch_bounds__(SCAN_T) void k2a_blocksum(
    const int* __restrict__ deg, int* __restrict__ bsum)
{
  const int tid = threadIdx.x;
  int idx = blockIdx.x * SCAN_T + tid;
  int v = (idx < N_NODES) ? deg[idx] : 0;
#pragma unroll
  for (int off = 32; off; off >>= 1) v += __shfl_xor(v, off, 64);
  __shared__ int ws_[16];
  if ((tid & 63) == 0) ws_[tid >> 6] = v;
  __syncthreads();
  if (tid == 0) {
    int s = 0;
    for (int i = 0; i < 16; i++) s += ws_[i];
    bsum[blockIdx.x] = s;
  }
}

__global__ __launch_bounds__(64) void k2b_scanb(
    const int* __restrict__ bsum, int* __restrict__ boff, int* __restrict__ offs)
{
  const int lane = threadIdx.x;
  int v = (lane < SCAN_NB) ? bsum[lane] : 0;
  int s = v;
#pragma unroll
  for (int off = 1; off < 64; off <<= 1) {
    int t = __shfl_up(s, off, 64);
    if (lane >= off) s += t;
  }
  if (lane < SCAN_NB) boff[lane] = s - v;     // exclusive block offset
  if (lane == SCAN_NB - 1) offs[N_NODES] = s; // total == N_EDGES
}

__global__ __launch_bounds__(SCAN_T) void k2c_apply(
    const int* __restrict__ deg, const int* __restrict__ boff,
    int* __restrict__ offs, int* __restrict__ cursor)
{
  __shared__ int lds[SCAN_T];
  const int tid = threadIdx.x;
  const int idx = blockIdx.x * SCAN_T + tid;
  int v = (idx < N_NODES) ? deg[idx] : 0;
  int s = v;
  lds[tid] = s;
  __syncthreads();
  for (int off = 1; off < SCAN_T; off <<= 1) {
    int t = (tid >= off) ? lds[tid - off] : 0;
    __syncthreads();
    s += t;
    lds[tid] = s;
    __syncthreads();
  }
  int excl = s - v + boff[blockIdx.x];
  if (idx < N_NODES) {
    offs[idx] = excl;
    cursor[idx] = excl;
  }
}

// ---------------- K3: scatter edges into CSR-by-dst ----------------
__global__ void k3_scatter(const int* __restrict__ src, const int* __restrict__ dst,
                           int* __restrict__ cursor, int* __restrict__ csr_src) {
  int e = blockIdx.x * blockDim.x + threadIdx.x;
  if (e < N_EDGES) {
    int d = dst[e];
    int pos = atomicAdd(&cursor[d], 1);
    csr_src[pos] = src[e];
  }
}

// ---------------- K4: per-dst softmax + weighted aggregation + head-mean ----------------
__global__ __launch_bounds__(256) void k4_agg(
    const int* __restrict__ offs, const int* __restrict__ csr_src,
    const float* __restrict__ el4, const float* __restrict__ er4,
    const float* __restrict__ feat, const float* __restrict__ bias,
    float* __restrict__ h_d)
{
  const int n = (blockIdx.x * blockDim.x + threadIdx.x) >> 6;  // wave per node
  const int lane = threadIdx.x & 63;
  if (n >= N_NODES) return;
  const int lo = offs[n], hi = offs[n + 1];
  const float4 erv = ((const float4*)er4)[n];

  // pass 1: per-head max
  float m0 = -INFINITY, m1 = -INFINITY, m2 = -INFINITY;
  for (int pos = lo + lane; pos < hi; pos += 64) {
    int s = csr_src[pos];
    float4 ev = ((const float4*)el4)[s];
    float e0 = ev.x + erv.x; e0 = e0 > 0.f ? e0 : NEG * e0;
    float e1 = ev.y + erv.y; e1 = e1 > 0.f ? e1 : NEG * e1;
    float e2 = ev.z + erv.z; e2 = e2 > 0.f ? e2 : NEG * e2;
    m0 = fmaxf(m0, e0); m1 = fmaxf(m1, e1); m2 = fmaxf(m2, e2);
  }
#pragma unroll
  for (int off = 32; off; off >>= 1) {
    m0 = fmaxf(m0, __shfl_xor(m0, off, 64));
    m1 = fmaxf(m1, __shfl_xor(m1, off, 64));
    m2 = fmaxf(m2, __shfl_xor(m2, off, 64));
  }

  // pass 2: per-head sum of exp
  float s0 = 0.f, s1 = 0.f, s2 = 0.f;
  for (int pos = lo + lane; pos < hi; pos += 64) {
    int s = csr_src[pos];
    float4 ev = ((const float4*)el4)[s];
    float e0 = ev.x + erv.x; e0 = e0 > 0.f ? e0 : NEG * e0;
    float e1 = ev.y + erv.y; e1 = e1 > 0.f ? e1 : NEG * e1;
    float e2 = ev.z + erv.z; e2 = e2 > 0.f ? e2 : NEG * e2;
    s0 += __expf(e0 - m0); s1 += __expf(e1 - m1); s2 += __expf(e2 - m2);
  }
#pragma unroll
  for (int off = 32; off; off >>= 1) {
    s0 += __shfl_xor(s0, off, 64);
    s1 += __shfl_xor(s1, off, 64);
    s2 += __shfl_xor(s2, off, 64);
  }
  const float i0 = s0 > 0.f ? 1.f / s0 : 0.f;
  const float i1 = s1 > 0.f ? 1.f / s1 : 0.f;
  const float i2 = s2 > 0.f ? 1.f / s2 : 0.f;

  // pass 3: aggregate alpha * feat[src]; lane owns dim `lane` for each head
  float a0 = 0.f, a1 = 0.f, a2 = 0.f;
  for (int base = lo; base < hi; base += 64) {
    const int cnt = min(64, hi - base);
    float w0 = 0.f, w1 = 0.f, w2 = 0.f;
    int sj = 0;
    if (lane < cnt) {
      sj = csr_src[base + lane];
      float4 ev = ((const float4*)el4)[sj];
      float e0 = ev.x + erv.x; e0 = e0 > 0.f ? e0 : NEG * e0;
      float e1 = ev.y + erv.y; e1 = e1 > 0.f ? e1 : NEG * e1;
      float e2 = ev.z + erv.z; e2 = e2 > 0.f ? e2 : NEG * e2;
      w0 = __expf(e0 - m0) * i0;
      w1 = __expf(e1 - m1) * i1;
      w2 = __expf(e2 - m2) * i2;
    }
    for (int j = 0; j < cnt; j++) {
      float b0 = __shfl(w0, j, 64);
      float b1 = __shfl(w1, j, 64);
      float b2 = __shfl(w2, j, 64);
      int ss = __shfl(sj, j, 64);
      const float* fr = feat + (size_t)ss * FEAT;
      a0 = fmaf(b0, fr[lane], a0);
      a1 = fmaf(b1, fr[64 + lane], a1);
      a2 = fmaf(b2, fr[128 + lane], a2);
    }
  }
  float o = (a0 + bias[lane] + a1 + bias[64 + lane] + a2 + bias[128 + lane]) * (1.f / 3.f);
  h_d[(size_t)n * HID + lane] = o;
}

// ---------------- K5: per-graph SUM pooling, grid-stride partials ----------------
#define K5_NPB 128
__global__ __launch_bounds__(256) void k5a_partial(
    const int* __restrict__ graph_id, const float* __restrict__ h_d,
    float* __restrict__ pooled_sum)
{
  const int wave = threadIdx.x >> 6, lane = threadIdx.x & 63;
  const int n0 = blockIdx.x * K5_NPB;
  const int n1 = min(n0 + K5_NPB, N_NODES);
  float acc = 0.f;
  int cur_g = -1;
  for (int i = n0 + wave; i < n1; i += 4) {
    int g = graph_id[i];  // sorted -> monotone along this walk
    if (g != cur_g) {
      if (cur_g >= 0) atomicAdd(&pooled_sum[cur_g * HID + lane], acc);
      acc = 0.f; cur_g = g;
    }
    acc += h_d[(size_t)i * HID + lane];
  }
  if (cur_g >= 0) atomicAdd(&pooled_sum[cur_g * HID + lane], acc);
}

// ---------------- K6: counts + mean, z @ lin1.T, concat, lin2, sigmoid ----------------
__global__ __launch_bounds__(256) void k6_final(
    const int* __restrict__ graph_id, const float* __restrict__ pooled_sum,
    const float* __restrict__ z,
    const float* __restrict__ lin1_w, const float* __restrict__ lin1_b,
    const float* __restrict__ lin2_w, const float* __restrict__ lin2_b,
    float* __restrict__ out)
{
  __shared__ float cat[N_GRAPHS][2 * HID];
  __shared__ float inv_cnt[N_GRAPHS];
  const int tid = threadIdx.x;
  if (tid < N_GRAPHS) {
    int g = tid;
    int lo, hi;
    { int l = 0, r = N_NODES; while (l < r) { int m = (l + r) >> 1; if (graph_id[m] < g) l = m + 1; else r = m; } lo = l; }
    { int l = 0, r = N_NODES; while (l < r) { int m = (l + r) >> 1; if (graph_id[m] < g + 1) l = m + 1; else r = m; } hi = l; }
    int cnt = hi - lo;
    inv_cnt[g] = 1.f / (float)(cnt > 0 ? cnt : 1);
  }
  __syncthreads();
  for (int i = tid; i < N_GRAPHS * HID; i += 256) {
    cat[i >> 6][i & 63] = pooled_sum[i] * inv_cnt[i >> 6];
  }
  for (int i = tid; i < N_GRAPHS * HID; i += 256) {
    int g = i >> 6, j = i & 63;
    float s = lin1_b[j];
    const float* zr = z + g * OUT_F;
    const float* wr = lin1_w + j * OUT_F;
    for (int k = 0; k < OUT_F; k += 4) {
      float4 zv = *(const float4*)(zr + k);
      float4 wv = *(const float4*)(wr + k);
      s = fmaf(zv.x, wv.x, fmaf(zv.y, wv.y, fmaf(zv.z, wv.z, fmaf(zv.w, wv.w, s))));
    }
    cat[g][HID + j] = s;
  }
  __syncthreads();
  if (tid < N_GRAPHS) {
    float s = lin2_b[0];
    for (int i = 0; i < 2 * HID; i++) s += cat[tid][i] * lin2_w[i];
    out[tid] = 1.f / (1.f + __expf(-s));
  }
}

extern "C" void kernel_launch(void* const* d_in, const int* in_sizes, int n_in,
                              void* d_out, int out_size, void* d_ws, size_t ws_size,
                              hipStream_t stream) {
  (void)in_sizes; (void)n_in; (void)out_size; (void)ws_size;
  const float* h      = (const float*)d_in[0];
  const float* z      = (const float*)d_in[1];
  const int*   src    = (const int*)d_in[2];
  const int*   dst    = (const int*)d_in[3];
  const int*   gid    = (const int*)d_in[4];
  const float* fc_w   = (const float*)d_in[5];
  const float* attn_l = (const float*)d_in[6];
  const float* attn_r = (const float*)d_in[7];
  const float* bias   = (const float*)d_in[8];
  const float* lin1_w = (const float*)d_in[9];
  const float* lin1_b = (const float*)d_in[10];
  const float* lin2_w = (const float*)d_in[11];
  const float* lin2_b = (const float*)d_in[12];
  float* out = (float*)d_out;

  // workspace layout (~57 MB)
  float* feat       = (float*)d_ws;                         // N*192
  float* el         = feat + (size_t)N_NODES * FEAT;        // N*4 (pad-4)
  float* er         = el + (size_t)N_NODES * 4;             // N*4
  float* h_d        = er + (size_t)N_NODES * 4;             // N*64
  float* pooled_sum = h_d + (size_t)N_NODES * HID;          // 16*64
  int* deg          = (int*)(pooled_sum + N_GRAPHS * HID);  // N+1
  int* offs         = deg + (N_NODES + 1);                  // N+1
  int* cursor       = offs + (N_NODES + 1);                 // N
  int* csr_src      = cursor + N_NODES;                     // E
  int* bsum         = csr_src + N_EDGES;                    // 49
  int* boff         = bsum + SCAN_NB;                       // 49

  hipMemsetAsync(deg, 0, (N_NODES + 1) * sizeof(int), stream);
  hipMemsetAsync(pooled_sum, 0, N_GRAPHS * HID * sizeof(float), stream);

  k0_gemm<<<N_NODES / K0_NB, 192, 0, stream>>>(h, fc_w, attn_l, attn_r, feat, el, er);
  k1_hist<<<N_EDGES / 256, 256, 0, stream>>>(dst, deg);
  k2a_blocksum<<<SCAN_NB, SCAN_T, 0, stream>>>(deg, bsum);
  k2b_scanb<<<1, 64, 0, stream>>>(bsum, boff, offs);
  k2c_apply<<<SCAN_NB, SCAN_T, 0, stream>>>(deg, boff, offs, cursor);
  k3_scatter<<<N_EDGES / 256, 256, 0, stream>>>(src, dst, cursor, csr_src);
  k4_agg<<<N_NODES / 4, 256, 0, stream>>>(offs, csr_src, el, er, feat, bias, h_d);
  k5a_partial<<<(N_NODES + K5_NPB - 1) / K5_NPB, 256, 0, stream>>>(gid, h_d, pooled_sum);
  k6_final<<<1, 256, 0, stream>>>(gid, pooled_sum, z, lin1_w, lin1_b, lin2_w, lin2_b, out);
}

// Round 3
// 348.247 us; speedup vs baseline: 1.9503x; 1.1043x over previous
//
#include <hip/hip_runtime.h>
#include <math.h>

#define N_NODES 50000
#define N_EDGES 800000
#define N_GRAPHS 16
#define NODE_F 128
#define HID 64
#define OUT_F 128
#define HEADS 3
#define NEG 0.2f
#define FEAT (HEADS*HID)  // 192

__device__ __forceinline__ ushort f2bf(float x) {
  union { float f; unsigned u; } v; v.f = x;
  unsigned r = v.u + 0x7fff + ((v.u >> 16) & 1);  // round-to-nearest-even
  return (ushort)(r >> 16);
}
__device__ __forceinline__ float bf2f(ushort x) {
  union { unsigned u; float f; } v; v.u = ((unsigned)x) << 16;
  return v.f;
}

// ---------------- K0: feat = h @ fc_w.T (bf16 out); el/er attention dots ----------------
// 192 threads, 32 nodes/block, 2 cols/thread -> 8 FMA per ds_read_b128 (FMA-bound)
#define K0_NB 32
__global__ __launch_bounds__(192) void k0_gemm(
    const float* __restrict__ h, const float* __restrict__ fc_w,
    const float* __restrict__ attn_l, const float* __restrict__ attn_r,
    ushort* __restrict__ feat, float* __restrict__ el, float* __restrict__ er)
{
  __shared__ float hs[K0_NB][NODE_F];  // 16 KB
  const int tid = threadIdx.x;
  const int n0 = blockIdx.x * K0_NB;
  for (int i = tid * 4; i < K0_NB * NODE_F; i += 192 * 4) {
    size_t gi = (size_t)n0 * NODE_F + i;
    if (n0 + (i >> 7) < N_NODES)
      *(float4*)&hs[0][i] = *(const float4*)(h + gi);
  }
  __syncthreads();

  const int s = (tid >= 96) ? 1 : 0;
  const int c = tid - s * 96;     // [0,96)
  const int col0 = 2 * c;         // global cols col0, col0+1
  const int nb = s * 16;          // node sub-group base

  float acc0[16], acc1[16];
#pragma unroll
  for (int m = 0; m < 16; m++) { acc0[m] = 0.f; acc1[m] = 0.f; }

  const float* w0 = fc_w + (size_t)col0 * NODE_F;
  const float* w1 = w0 + NODE_F;
  for (int k = 0; k < NODE_F; k += 4) {
    float4 wa = *(const float4*)(w0 + k);
    float4 wb = *(const float4*)(w1 + k);
#pragma unroll
    for (int m = 0; m < 16; m++) {
      float4 h4 = *(const float4*)(&hs[nb + m][k]);
      acc0[m] = fmaf(wa.x, h4.x, fmaf(wa.y, h4.y, fmaf(wa.z, h4.z, fmaf(wa.w, h4.w, acc0[m]))));
      acc1[m] = fmaf(wb.x, h4.x, fmaf(wb.y, h4.y, fmaf(wb.z, h4.z, fmaf(wb.w, h4.w, acc1[m]))));
    }
  }

#pragma unroll
  for (int m = 0; m < 16; m++) {
    int n = n0 + nb + m;
    if (n < N_NODES) {
      ushort2 v; v.x = f2bf(acc0[m]); v.y = f2bf(acc1[m]);
      *(ushort2*)(feat + (size_t)n * FEAT + col0) = v;
    }
  }

  // el/er: each (head, node-group) owned by an aligned 32-lane group.
  const int head = c >> 5;  // 0..2
  const float al0 = attn_l[col0], al1 = attn_l[col0 + 1];
  const float ar0 = attn_r[col0], ar1 = attn_r[col0 + 1];
#pragma unroll
  for (int m = 0; m < 16; m++) {
    float vl = fmaf(acc0[m], al0, acc1[m] * al1);
    float vr = fmaf(acc0[m], ar0, acc1[m] * ar1);
#pragma unroll
    for (int off = 16; off; off >>= 1) {
      vl += __shfl_xor(vl, off, 64);
      vr += __shfl_xor(vr, off, 64);
    }
    int n = n0 + nb + m;
    if ((tid & 31) == 0 && n < N_NODES) {
      el[(size_t)n * 4 + head] = vl;   // stride-4 pad so K4 can float4-load
      er[(size_t)n * 4 + head] = vr;
    }
  }
}

// ---------------- K1: in-degree histogram ----------------
__global__ void k1_hist(const int* __restrict__ dst, int* __restrict__ deg) {
  int e = blockIdx.x * blockDim.x + threadIdx.x;
  if (e < N_EDGES) atomicAdd(&deg[dst[e]], 1);
}

// ---------------- K2: coalesced 3-stage exclusive scan ----------------
#define SCAN_T 1024
#define SCAN_NB 49  // ceil(50000/1024)

__global__ __launch_bounds__(SCAN_T) void k2a_blocksum(
    const int* __restrict__ deg, int* __restrict__ bsum)
{
  const int tid = threadIdx.x;
  int idx = blockIdx.x * SCAN_T + tid;
  int v = (idx < N_NODES) ? deg[idx] : 0;
#pragma unroll
  for (int off = 32; off; off >>= 1) v += __shfl_xor(v, off, 64);
  __shared__ int ws_[16];
  if ((tid & 63) == 0) ws_[tid >> 6] = v;
  __syncthreads();
  if (tid == 0) {
    int s = 0;
    for (int i = 0; i < 16; i++) s += ws_[i];
    bsum[blockIdx.x] = s;
  }
}

__global__ __launch_bounds__(64) void k2b_scanb(
    const int* __restrict__ bsum, int* __restrict__ boff, int* __restrict__ offs)
{
  const int lane = threadIdx.x;
  int v = (lane < SCAN_NB) ? bsum[lane] : 0;
  int s = v;
#pragma unroll
  for (int off = 1; off < 64; off <<= 1) {
    int t = __shfl_up(s, off, 64);
    if (lane >= off) s += t;
  }
  if (lane < SCAN_NB) boff[lane] = s - v;     // exclusive block offset
  if (lane == SCAN_NB - 1) offs[N_NODES] = s; // total == N_EDGES
}

__global__ __launch_bounds__(SCAN_T) void k2c_apply(
    const int* __restrict__ deg, const int* __restrict__ boff,
    int* __restrict__ offs, int* __restrict__ cursor)
{
  __shared__ int lds[SCAN_T];
  const int tid = threadIdx.x;
  const int idx = blockIdx.x * SCAN_T + tid;
  int v = (idx < N_NODES) ? deg[idx] : 0;
  int s = v;
  lds[tid] = s;
  __syncthreads();
  for (int off = 1; off < SCAN_T; off <<= 1) {
    int t = (tid >= off) ? lds[tid - off] : 0;
    __syncthreads();
    s += t;
    lds[tid] = s;
    __syncthreads();
  }
  int excl = s - v + boff[blockIdx.x];
  if (idx < N_NODES) {
    offs[idx] = excl;
    cursor[idx] = excl;
  }
}

// ---------------- K3: scatter edges into CSR-by-dst ----------------
__global__ void k3_scatter(const int* __restrict__ src, const int* __restrict__ dst,
                           int* __restrict__ cursor, int* __restrict__ csr_src) {
  int e = blockIdx.x * blockDim.x + threadIdx.x;
  if (e < N_EDGES) {
    int d = dst[e];
    int pos = atomicAdd(&cursor[d], 1);
    csr_src[pos] = src[e];
  }
}

// ---------------- K4: per-dst softmax (no max-shift) + aggregation + head-mean ----------------
__global__ __launch_bounds__(256) void k4_agg(
    const int* __restrict__ offs, const int* __restrict__ csr_src,
    const float* __restrict__ el4, const float* __restrict__ er4,
    const ushort* __restrict__ feat, const float* __restrict__ bias,
    float* __restrict__ h_d)
{
  const int n = (blockIdx.x * blockDim.x + threadIdx.x) >> 6;  // wave per node
  const int lane = threadIdx.x & 63;
  if (n >= N_NODES) return;
  const int lo = offs[n], hi = offs[n + 1];
  const float4 erv = ((const float4*)er4)[n];

  // pass 1: per-head sum of exp (|e| <= ~7, no overflow -> skip max-shift)
  float s0 = 0.f, s1 = 0.f, s2 = 0.f;
  for (int pos = lo + lane; pos < hi; pos += 64) {
    int s = csr_src[pos];
    float4 ev = ((const float4*)el4)[s];
    float e0 = ev.x + erv.x; e0 = e0 > 0.f ? e0 : NEG * e0;
    float e1 = ev.y + erv.y; e1 = e1 > 0.f ? e1 : NEG * e1;
    float e2 = ev.z + erv.z; e2 = e2 > 0.f ? e2 : NEG * e2;
    s0 += __expf(e0); s1 += __expf(e1); s2 += __expf(e2);
  }
#pragma unroll
  for (int off = 32; off; off >>= 1) {
    s0 += __shfl_xor(s0, off, 64);
    s1 += __shfl_xor(s1, off, 64);
    s2 += __shfl_xor(s2, off, 64);
  }
  const float i0 = s0 > 0.f ? 1.f / s0 : 0.f;
  const float i1 = s1 > 0.f ? 1.f / s1 : 0.f;
  const float i2 = s2 > 0.f ? 1.f / s2 : 0.f;

  // pass 2: aggregate alpha * feat[src] (bf16 rows); lane owns dim `lane` per head
  float a0 = 0.f, a1 = 0.f, a2 = 0.f;
  for (int base = lo; base < hi; base += 64) {
    const int cnt = min(64, hi - base);
    float w0 = 0.f, w1 = 0.f, w2 = 0.f;
    int sj = 0;
    if (lane < cnt) {
      sj = csr_src[base + lane];
      float4 ev = ((const float4*)el4)[sj];
      float e0 = ev.x + erv.x; e0 = e0 > 0.f ? e0 : NEG * e0;
      float e1 = ev.y + erv.y; e1 = e1 > 0.f ? e1 : NEG * e1;
      float e2 = ev.z + erv.z; e2 = e2 > 0.f ? e2 : NEG * e2;
      w0 = __expf(e0) * i0;
      w1 = __expf(e1) * i1;
      w2 = __expf(e2) * i2;
    }
    for (int j = 0; j < cnt; j++) {
      float b0 = __shfl(w0, j, 64);
      float b1 = __shfl(w1, j, 64);
      float b2 = __shfl(w2, j, 64);
      int ss = __shfl(sj, j, 64);
      const ushort* fr = feat + (size_t)ss * FEAT;
      a0 = fmaf(b0, bf2f(fr[lane]), a0);
      a1 = fmaf(b1, bf2f(fr[64 + lane]), a1);
      a2 = fmaf(b2, bf2f(fr[128 + lane]), a2);
    }
  }
  float o = (a0 + bias[lane] + a1 + bias[64 + lane] + a2 + bias[128 + lane]) * (1.f / 3.f);
  h_d[(size_t)n * HID + lane] = o;
}

// ---------------- K5: per-graph SUM pooling, grid-stride partials ----------------
#define K5_NPB 128
__global__ __launch_bounds__(256) void k5a_partial(
    const int* __restrict__ graph_id, const float* __restrict__ h_d,
    float* __restrict__ pooled_sum)
{
  const int wave = threadIdx.x >> 6, lane = threadIdx.x & 63;
  const int n0 = blockIdx.x * K5_NPB;
  const int n1 = min(n0 + K5_NPB, N_NODES);
  float acc = 0.f;
  int cur_g = -1;
  for (int i = n0 + wave; i < n1; i += 4) {
    int g = graph_id[i];  // sorted -> monotone along this walk
    if (g != cur_g) {
      if (cur_g >= 0) atomicAdd(&pooled_sum[cur_g * HID + lane], acc);
      acc = 0.f; cur_g = g;
    }
    acc += h_d[(size_t)i * HID + lane];
  }
  if (cur_g >= 0) atomicAdd(&pooled_sum[cur_g * HID + lane], acc);
}

// ---------------- K6: counts + mean, z @ lin1.T, concat, lin2, sigmoid ----------------
__global__ __launch_bounds__(256) void k6_final(
    const int* __restrict__ graph_id, const float* __restrict__ pooled_sum,
    const float* __restrict__ z,
    const float* __restrict__ lin1_w, const float* __restrict__ lin1_b,
    const float* __restrict__ lin2_w, const float* __restrict__ lin2_b,
    float* __restrict__ out)
{
  __shared__ float cat[N_GRAPHS][2 * HID];
  __shared__ float inv_cnt[N_GRAPHS];
  const int tid = threadIdx.x;
  if (tid < N_GRAPHS) {
    int g = tid;
    int lo, hi;
    { int l = 0, r = N_NODES; while (l < r) { int m = (l + r) >> 1; if (graph_id[m] < g) l = m + 1; else r = m; } lo = l; }
    { int l = 0, r = N_NODES; while (l < r) { int m = (l + r) >> 1; if (graph_id[m] < g + 1) l = m + 1; else r = m; } hi = l; }
    int cnt = hi - lo;
    inv_cnt[g] = 1.f / (float)(cnt > 0 ? cnt : 1);
  }
  __syncthreads();
  for (int i = tid; i < N_GRAPHS * HID; i += 256) {
    cat[i >> 6][i & 63] = pooled_sum[i] * inv_cnt[i >> 6];
  }
  for (int i = tid; i < N_GRAPHS * HID; i += 256) {
    int g = i >> 6, j = i & 63;
    float s = lin1_b[j];
    const float* zr = z + g * OUT_F;
    const float* wr = lin1_w + j * OUT_F;
    for (int k = 0; k < OUT_F; k += 4) {
      float4 zv = *(const float4*)(zr + k);
      float4 wv = *(const float4*)(wr + k);
      s = fmaf(zv.x, wv.x, fmaf(zv.y, wv.y, fmaf(zv.z, wv.z, fmaf(zv.w, wv.w, s))));
    }
    cat[g][HID + j] = s;
  }
  __syncthreads();
  if (tid < N_GRAPHS) {
    float s = lin2_b[0];
    for (int i = 0; i < 2 * HID; i++) s += cat[tid][i] * lin2_w[i];
    out[tid] = 1.f / (1.f + __expf(-s));
  }
}

extern "C" void kernel_launch(void* const* d_in, const int* in_sizes, int n_in,
                              void* d_out, int out_size, void* d_ws, size_t ws_size,
                              hipStream_t stream) {
  (void)in_sizes; (void)n_in; (void)out_size; (void)ws_size;
  const float* h      = (const float*)d_in[0];
  const float* z      = (const float*)d_in[1];
  const int*   src    = (const int*)d_in[2];
  const int*   dst    = (const int*)d_in[3];
  const int*   gid    = (const int*)d_in[4];
  const float* fc_w   = (const float*)d_in[5];
  const float* attn_l = (const float*)d_in[6];
  const float* attn_r = (const float*)d_in[7];
  const float* bias   = (const float*)d_in[8];
  const float* lin1_w = (const float*)d_in[9];
  const float* lin1_b = (const float*)d_in[10];
  const float* lin2_w = (const float*)d_in[11];
  const float* lin2_b = (const float*)d_in[12];
  float* out = (float*)d_out;

  // workspace layout (~40 MB)
  ushort* feat      = (ushort*)d_ws;                        // N*192 bf16 (19.2 MB)
  float* el         = (float*)(feat + (size_t)N_NODES * FEAT);
  float* er         = el + (size_t)N_NODES * 4;             // N*4
  float* h_d        = er + (size_t)N_NODES * 4;             // N*64
  float* pooled_sum = h_d + (size_t)N_NODES * HID;          // 16*64
  int* deg          = (int*)(pooled_sum + N_GRAPHS * HID);  // N+1
  int* offs         = deg + (N_NODES + 1);                  // N+1
  int* cursor       = offs + (N_NODES + 1);                 // N
  int* csr_src      = cursor + N_NODES;                     // E
  int* bsum         = csr_src + N_EDGES;                    // 49
  int* boff         = bsum + SCAN_NB;                       // 49

  hipMemsetAsync(deg, 0, (N_NODES + 1) * sizeof(int), stream);
  hipMemsetAsync(pooled_sum, 0, N_GRAPHS * HID * sizeof(float), stream);

  k0_gemm<<<(N_NODES + K0_NB - 1) / K0_NB, 192, 0, stream>>>(h, fc_w, attn_l, attn_r, feat, el, er);
  k1_hist<<<N_EDGES / 256, 256, 0, stream>>>(dst, deg);
  k2a_blocksum<<<SCAN_NB, SCAN_T, 0, stream>>>(deg, bsum);
  k2b_scanb<<<1, 64, 0, stream>>>(bsum, boff, offs);
  k2c_apply<<<SCAN_NB, SCAN_T, 0, stream>>>(deg, boff, offs, cursor);
  k3_scatter<<<N_EDGES / 256, 256, 0, stream>>>(src, dst, cursor, csr_src);
  k4_agg<<<N_NODES / 4, 256, 0, stream>>>(offs, csr_src, el, er, feat, bias, h_d);
  k5a_partial<<<(N_NODES + K5_NPB - 1) / K5_NPB, 256, 0, stream>>>(gid, h_d, pooled_sum);
  k6_final<<<1, 256, 0, stream>>>(gid, pooled_sum, z, lin1_w, lin1_b, lin2_w, lin2_b, out);
}

// Round 4
// 317.915 us; speedup vs baseline: 2.1364x; 1.0954x over previous
//
#include <hip/hip_runtime.h>
#include <math.h>

#define N_NODES 50000
#define N_EDGES 800000
#define N_GRAPHS 16
#define NODE_F 128
#define HID 64
#define OUT_F 128
#define HEADS 3
#define NEG 0.2f
#define FEAT (HEADS*HID)  // 192

typedef float f32x4 __attribute__((ext_vector_type(4)));
typedef short bf16x8 __attribute__((ext_vector_type(8)));

__device__ __forceinline__ ushort f2bf(float x) {
  union { float f; unsigned u; } v; v.f = x;
  unsigned r = v.u + 0x7fff + ((v.u >> 16) & 1);  // round-to-nearest-even
  return (ushort)(r >> 16);
}
__device__ __forceinline__ float bf2f(ushort x) {
  union { unsigned u; float f; } v; v.u = ((unsigned)x) << 16;
  return v.f;
}

// ---------------- K0: feat = h @ fc_w.T via MFMA bf16; el/er in epilogue ----------------
// 64-node tile, 4 waves; A staged full-K, B staged per-32-K slice. 32 KB LDS.
__global__ __launch_bounds__(256) void k0_mfma(
    const float* __restrict__ h, const float* __restrict__ fc_w,
    const float* __restrict__ attn_l, const float* __restrict__ attn_r,
    ushort* __restrict__ feat, float* __restrict__ el, float* __restrict__ er)
{
  __shared__ ushort A[64][136];   // bf16, 272 B row stride (16-B aligned, 2-way banks)
  __shared__ ushort Bs[192][40];  // bf16 K-slice, 80 B row stride
  const int tid = threadIdx.x;
  const int n0 = blockIdx.x * 64;

  // stage A: h[n0..n0+64) x 128, fp32 -> bf16
  for (int i = tid; i < 64 * 32; i += 256) {
    int r = i >> 5, c4 = i & 31;
    if (n0 + r < N_NODES) {
      float4 v = *(const float4*)(h + (size_t)(n0 + r) * NODE_F + c4 * 4);
      unsigned lo = f2bf(v.x) | ((unsigned)f2bf(v.y) << 16);
      unsigned hi = f2bf(v.z) | ((unsigned)f2bf(v.w) << 16);
      *(uint2*)&A[r][c4 * 4] = make_uint2(lo, hi);
    }
  }

  const int lane = tid & 63, wv = tid >> 6;
  const int m = lane & 15, kq = lane >> 4;

  f32x4 acc[12];
#pragma unroll
  for (int t = 0; t < 12; t++) acc[t] = (f32x4){0.f, 0.f, 0.f, 0.f};

  for (int kk = 0; kk < 4; kk++) {
    __syncthreads();  // protect Bs from previous iteration's readers (and A writes, iter 0)
    for (int i = tid; i < 192 * 8; i += 256) {
      int r = i >> 3, c4 = i & 7;
      float4 v = *(const float4*)(fc_w + (size_t)r * NODE_F + kk * 32 + c4 * 4);
      unsigned lo = f2bf(v.x) | ((unsigned)f2bf(v.y) << 16);
      unsigned hi = f2bf(v.z) | ((unsigned)f2bf(v.w) << 16);
      *(uint2*)&Bs[r][c4 * 4] = make_uint2(lo, hi);
    }
    __syncthreads();
    // A-frag: A[m=lane&15][k = kq*8 + j]  (m120-verified layout)
    bf16x8 af = *(const bf16x8*)&A[wv * 16 + m][kk * 32 + kq * 8];
#pragma unroll
    for (int t = 0; t < 12; t++) {
      bf16x8 bf = *(const bf16x8*)&Bs[t * 16 + m][kq * 8];  // B-col = lane&15
      acc[t] = __builtin_amdgcn_mfma_f32_16x16x32_bf16(af, bf, acc[t], 0, 0, 0);
    }
  }

  // epilogue: C/D layout col=lane&15, row=(lane>>4)*4+reg (m89-verified)
  const int rbase = n0 + wv * 16 + kq * 4;
#pragma unroll
  for (int t = 0; t < 12; t++) {
#pragma unroll
    for (int reg = 0; reg < 4; reg++) {
      int n = rbase + reg;
      if (n < N_NODES) feat[(size_t)n * FEAT + t * 16 + m] = f2bf(acc[t][reg]);
    }
  }

  // el/er from fp32 accumulators: head h <- tiles 4h..4h+3
#pragma unroll
  for (int hh = 0; hh < HEADS; hh++) {
    float elv[4] = {0.f, 0.f, 0.f, 0.f};
    float erv[4] = {0.f, 0.f, 0.f, 0.f};
#pragma unroll
    for (int tt = 0; tt < 4; tt++) {
      int t = hh * 4 + tt;
      float al = attn_l[hh * HID + tt * 16 + m];
      float ar = attn_r[hh * HID + tt * 16 + m];
#pragma unroll
      for (int reg = 0; reg < 4; reg++) {
        elv[reg] = fmaf(acc[t][reg], al, elv[reg]);
        erv[reg] = fmaf(acc[t][reg], ar, erv[reg]);
      }
    }
#pragma unroll
    for (int reg = 0; reg < 4; reg++) {
#pragma unroll
      for (int off = 1; off < 16; off <<= 1) {  // reduce over the 16-lane col group
        elv[reg] += __shfl_xor(elv[reg], off, 64);
        erv[reg] += __shfl_xor(erv[reg], off, 64);
      }
      int n = rbase + reg;
      if (m == 0 && n < N_NODES) {
        el[(size_t)n * 4 + hh] = elv[reg];
        er[(size_t)n * 4 + hh] = erv[reg];
      }
    }
  }
}

// ---------------- K1: in-degree histogram ----------------
__global__ void k1_hist(const int* __restrict__ dst, int* __restrict__ deg) {
  int e = blockIdx.x * blockDim.x + threadIdx.x;
  if (e < N_EDGES) atomicAdd(&deg[dst[e]], 1);
}

// ---------------- K2: coalesced 3-stage exclusive scan ----------------
#define SCAN_T 1024
#define SCAN_NB 49  // ceil(50000/1024)

__global__ __launch_bounds__(SCAN_T) void k2a_blocksum(
    const int* __restrict__ deg, int* __restrict__ bsum)
{
  const int tid = threadIdx.x;
  int idx = blockIdx.x * SCAN_T + tid;
  int v = (idx < N_NODES) ? deg[idx] : 0;
#pragma unroll
  for (int off = 32; off; off >>= 1) v += __shfl_xor(v, off, 64);
  __shared__ int ws_[16];
  if ((tid & 63) == 0) ws_[tid >> 6] = v;
  __syncthreads();
  if (tid == 0) {
    int s = 0;
    for (int i = 0; i < 16; i++) s += ws_[i];
    bsum[blockIdx.x] = s;
  }
}

__global__ __launch_bounds__(64) void k2b_scanb(
    const int* __restrict__ bsum, int* __restrict__ boff, int* __restrict__ offs)
{
  const int lane = threadIdx.x;
  int v = (lane < SCAN_NB) ? bsum[lane] : 0;
  int s = v;
#pragma unroll
  for (int off = 1; off < 64; off <<= 1) {
    int t = __shfl_up(s, off, 64);
    if (lane >= off) s += t;
  }
  if (lane < SCAN_NB) boff[lane] = s - v;     // exclusive block offset
  if (lane == SCAN_NB - 1) offs[N_NODES] = s; // total == N_EDGES
}

__global__ __launch_bounds__(SCAN_T) void k2c_apply(
    const int* __restrict__ deg, const int* __restrict__ boff,
    int* __restrict__ offs, int* __restrict__ cursor)
{
  __shared__ int lds[SCAN_T];
  const int tid = threadIdx.x;
  const int idx = blockIdx.x * SCAN_T + tid;
  int v = (idx < N_NODES) ? deg[idx] : 0;
  int s = v;
  lds[tid] = s;
  __syncthreads();
  for (int off = 1; off < SCAN_T; off <<= 1) {
    int t = (tid >= off) ? lds[tid - off] : 0;
    __syncthreads();
    s += t;
    lds[tid] = s;
    __syncthreads();
  }
  int excl = s - v + boff[blockIdx.x];
  if (idx < N_NODES) {
    offs[idx] = excl;
    cursor[idx] = excl;
  }
}

// ---------------- K3: scatter edges into CSR-by-dst ----------------
__global__ void k3_scatter(const int* __restrict__ src, const int* __restrict__ dst,
                           int* __restrict__ cursor, int* __restrict__ csr_src) {
  int e = blockIdx.x * blockDim.x + threadIdx.x;
  if (e < N_EDGES) {
    int d = dst[e];
    int pos = atomicAdd(&cursor[d], 1);
    csr_src[pos] = src[e];
  }
}

// ---------------- K4: per-dst softmax (no max-shift) + aggregation + head-mean ----------------
__global__ __launch_bounds__(256) void k4_agg(
    const int* __restrict__ offs, const int* __restrict__ csr_src,
    const float* __restrict__ el4, const float* __restrict__ er4,
    const ushort* __restrict__ feat, const float* __restrict__ bias,
    float* __restrict__ h_d)
{
  const int n = (blockIdx.x * blockDim.x + threadIdx.x) >> 6;  // wave per node
  const int lane = threadIdx.x & 63;
  if (n >= N_NODES) return;
  const int lo = offs[n], hi = offs[n + 1];
  const float4 erv = ((const float4*)er4)[n];

  // pass 1: per-head sum of exp (|e| <= ~7, no overflow -> skip max-shift)
  float s0 = 0.f, s1 = 0.f, s2 = 0.f;
  for (int pos = lo + lane; pos < hi; pos += 64) {
    int s = csr_src[pos];
    float4 ev = ((const float4*)el4)[s];
    float e0 = ev.x + erv.x; e0 = e0 > 0.f ? e0 : NEG * e0;
    float e1 = ev.y + erv.y; e1 = e1 > 0.f ? e1 : NEG * e1;
    float e2 = ev.z + erv.z; e2 = e2 > 0.f ? e2 : NEG * e2;
    s0 += __expf(e0); s1 += __expf(e1); s2 += __expf(e2);
  }
#pragma unroll
  for (int off = 32; off; off >>= 1) {
    s0 += __shfl_xor(s0, off, 64);
    s1 += __shfl_xor(s1, off, 64);
    s2 += __shfl_xor(s2, off, 64);
  }
  const float i0 = s0 > 0.f ? 1.f / s0 : 0.f;
  const float i1 = s1 > 0.f ? 1.f / s1 : 0.f;
  const float i2 = s2 > 0.f ? 1.f / s2 : 0.f;

  // pass 2: aggregate alpha * feat[src] (bf16 rows); lane owns dim `lane` per head
  float a0 = 0.f, a1 = 0.f, a2 = 0.f;
  for (int base = lo; base < hi; base += 64) {
    const int cnt = min(64, hi - base);
    float w0 = 0.f, w1 = 0.f, w2 = 0.f;
    int sj = 0;
    if (lane < cnt) {
      sj = csr_src[base + lane];
      float4 ev = ((const float4*)el4)[sj];
      float e0 = ev.x + erv.x; e0 = e0 > 0.f ? e0 : NEG * e0;
      float e1 = ev.y + erv.y; e1 = e1 > 0.f ? e1 : NEG * e1;
      float e2 = ev.z + erv.z; e2 = e2 > 0.f ? e2 : NEG * e2;
      w0 = __expf(e0) * i0;
      w1 = __expf(e1) * i1;
      w2 = __expf(e2) * i2;
    }
    for (int j = 0; j < cnt; j++) {
      float b0 = __shfl(w0, j, 64);
      float b1 = __shfl(w1, j, 64);
      float b2 = __shfl(w2, j, 64);
      int ss = __shfl(sj, j, 64);
      const ushort* fr = feat + (size_t)ss * FEAT;
      a0 = fmaf(b0, bf2f(fr[lane]), a0);
      a1 = fmaf(b1, bf2f(fr[64 + lane]), a1);
      a2 = fmaf(b2, bf2f(fr[128 + lane]), a2);
    }
  }
  float o = (a0 + bias[lane] + a1 + bias[64 + lane] + a2 + bias[128 + lane]) * (1.f / 3.f);
  h_d[(size_t)n * HID + lane] = o;
}

// ---------------- K5: per-graph SUM pooling, grid-stride partials ----------------
#define K5_NPB 128
__global__ __launch_bounds__(256) void k5a_partial(
    const int* __restrict__ graph_id, const float* __restrict__ h_d,
    float* __restrict__ pooled_sum)
{
  const int wave = threadIdx.x >> 6, lane = threadIdx.x & 63;
  const int n0 = blockIdx.x * K5_NPB;
  const int n1 = min(n0 + K5_NPB, N_NODES);
  float acc = 0.f;
  int cur_g = -1;
  for (int i = n0 + wave; i < n1; i += 4) {
    int g = graph_id[i];  // sorted -> monotone along this walk
    if (g != cur_g) {
      if (cur_g >= 0) atomicAdd(&pooled_sum[cur_g * HID + lane], acc);
      acc = 0.f; cur_g = g;
    }
    acc += h_d[(size_t)i * HID + lane];
  }
  if (cur_g >= 0) atomicAdd(&pooled_sum[cur_g * HID + lane], acc);
}

// ---------------- K6: counts + mean, z @ lin1.T, concat, lin2, sigmoid ----------------
__global__ __launch_bounds__(256) void k6_final(
    const int* __restrict__ graph_id, const float* __restrict__ pooled_sum,
    const float* __restrict__ z,
    const float* __restrict__ lin1_w, const float* __restrict__ lin1_b,
    const float* __restrict__ lin2_w, const float* __restrict__ lin2_b,
    float* __restrict__ out)
{
  __shared__ float cat[N_GRAPHS][2 * HID];
  __shared__ float inv_cnt[N_GRAPHS];
  const int tid = threadIdx.x;
  if (tid < N_GRAPHS) {
    int g = tid;
    int lo, hi;
    { int l = 0, r = N_NODES; while (l < r) { int m = (l + r) >> 1; if (graph_id[m] < g) l = m + 1; else r = m; } lo = l; }
    { int l = 0, r = N_NODES; while (l < r) { int m = (l + r) >> 1; if (graph_id[m] < g + 1) l = m + 1; else r = m; } hi = l; }
    int cnt = hi - lo;
    inv_cnt[g] = 1.f / (float)(cnt > 0 ? cnt : 1);
  }
  __syncthreads();
  for (int i = tid; i < N_GRAPHS * HID; i += 256) {
    cat[i >> 6][i & 63] = pooled_sum[i] * inv_cnt[i >> 6];
  }
  for (int i = tid; i < N_GRAPHS * HID; i += 256) {
    int g = i >> 6, j = i & 63;
    float s = lin1_b[j];
    const float* zr = z + g * OUT_F;
    const float* wr = lin1_w + j * OUT_F;
    for (int k = 0; k < OUT_F; k += 4) {
      float4 zv = *(const float4*)(zr + k);
      float4 wv = *(const float4*)(wr + k);
      s = fmaf(zv.x, wv.x, fmaf(zv.y, wv.y, fmaf(zv.z, wv.z, fmaf(zv.w, wv.w, s))));
    }
    cat[g][HID + j] = s;
  }
  __syncthreads();
  if (tid < N_GRAPHS) {
    float s = lin2_b[0];
    for (int i = 0; i < 2 * HID; i++) s += cat[tid][i] * lin2_w[i];
    out[tid] = 1.f / (1.f + __expf(-s));
  }
}

extern "C" void kernel_launch(void* const* d_in, const int* in_sizes, int n_in,
                              void* d_out, int out_size, void* d_ws, size_t ws_size,
                              hipStream_t stream) {
  (void)in_sizes; (void)n_in; (void)out_size; (void)ws_size;
  const float* h      = (const float*)d_in[0];
  const float* z      = (const float*)d_in[1];
  const int*   src    = (const int*)d_in[2];
  const int*   dst    = (const int*)d_in[3];
  const int*   gid    = (const int*)d_in[4];
  const float* fc_w   = (const float*)d_in[5];
  const float* attn_l = (const float*)d_in[6];
  const float* attn_r = (const float*)d_in[7];
  const float* bias   = (const float*)d_in[8];
  const float* lin1_w = (const float*)d_in[9];
  const float* lin1_b = (const float*)d_in[10];
  const float* lin2_w = (const float*)d_in[11];
  const float* lin2_b = (const float*)d_in[12];
  float* out = (float*)d_out;

  // workspace layout (~40 MB)
  ushort* feat      = (ushort*)d_ws;                        // N*192 bf16 (19.2 MB)
  float* el         = (float*)(feat + (size_t)N_NODES * FEAT);
  float* er         = el + (size_t)N_NODES * 4;             // N*4
  float* h_d        = er + (size_t)N_NODES * 4;             // N*64
  float* pooled_sum = h_d + (size_t)N_NODES * HID;          // 16*64
  int* deg          = (int*)(pooled_sum + N_GRAPHS * HID);  // N+1
  int* offs         = deg + (N_NODES + 1);                  // N+1
  int* cursor       = offs + (N_NODES + 1);                 // N
  int* csr_src      = cursor + N_NODES;                     // E
  int* bsum         = csr_src + N_EDGES;                    // 49
  int* boff         = bsum + SCAN_NB;                       // 49

  hipMemsetAsync(deg, 0, (N_NODES + 1) * sizeof(int), stream);
  hipMemsetAsync(pooled_sum, 0, N_GRAPHS * HID * sizeof(float), stream);

  k0_mfma<<<(N_NODES + 63) / 64, 256, 0, stream>>>(h, fc_w, attn_l, attn_r, feat, el, er);
  k1_hist<<<N_EDGES / 256, 256, 0, stream>>>(dst, deg);
  k2a_blocksum<<<SCAN_NB, SCAN_T, 0, stream>>>(deg, bsum);
  k2b_scanb<<<1, 64, 0, stream>>>(bsum, boff, offs);
  k2c_apply<<<SCAN_NB, SCAN_T, 0, stream>>>(deg, boff, offs, cursor);
  k3_scatter<<<N_EDGES / 256, 256, 0, stream>>>(src, dst, cursor, csr_src);
  k4_agg<<<N_NODES / 4, 256, 0, stream>>>(offs, csr_src, el, er, feat, bias, h_d);
  k5a_partial<<<(N_NODES + K5_NPB - 1) / K5_NPB, 256, 0, stream>>>(gid, h_d, pooled_sum);
  k6_final<<<1, 256, 0, stream>>>(gid, pooled_sum, z, lin1_w, lin1_b, lin2_w, lin2_b, out);
}